// Round 1
// baseline (163.539 us; speedup 1.0000x reference)
//
#include <hip/hip_runtime.h>
#include <stdint.h>

#define BM 128
#define NTHREADS 256

typedef __attribute__((ext_vector_type(8))) short short8;
typedef __attribute__((ext_vector_type(4))) float f32x4;

__device__ __forceinline__ unsigned short f2bf(float f) {
  union { float f; uint32_t u; } v; v.f = f;
  uint32_t u = v.u;
  uint32_t r = (u + 0x7FFFu + ((u >> 16) & 1u)) >> 16;
  return (unsigned short)r;
}

// H[E,128] = relu(concat(src,dst)[E,256] @ W1[256,128] + b1); out = sigmoid(H @ W2 + b2)
__global__ __launch_bounds__(NTHREADS, 2)
void edge_decoder_kernel(const float* __restrict__ src_emb,
                         const float* __restrict__ dst_emb,
                         const int* __restrict__ eidx,
                         const float* __restrict__ W1,
                         const float* __restrict__ b1,
                         const float* __restrict__ W2,
                         const float* __restrict__ b2,
                         float* __restrict__ out,
                         int E, int ntiles) {
  // A-tile: BM rows x 256 bf16 (512 B/row), XOR-swizzled within 128B windows
  __shared__ char Als[BM * 512];       // 64 KB
  __shared__ float rowpart[4][BM];     // 2 KB

  const int tid  = threadIdx.x;
  const int lane = tid & 63;
  const int w    = tid >> 6;           // wave id 0..3, owns cols [w*32, w*32+32)
  const int l15  = lane & 15;
  const int lk8  = (lane >> 4) * 8;    // k-offset within 32-K block

  // ---- B fragments (W1) -> registers, bf16. B[k][n]: lane = n + 16*(k>>3), slot k&7 ----
  short8 bfrag[8][2];
#pragma unroll
  for (int s = 0; s < 8; ++s) {
#pragma unroll
    for (int nf = 0; nf < 2; ++nf) {
      const int col = w * 32 + nf * 16 + l15;
      short8 t;
#pragma unroll
      for (int j = 0; j < 8; ++j) {
        const int k = s * 32 + lk8 + j;
        t[j] = (short)f2bf(W1[k * 128 + col]);
      }
      bfrag[s][nf] = t;
    }
  }
  float b1v[2], w2v[2];
#pragma unroll
  for (int nf = 0; nf < 2; ++nf) {
    const int col = w * 32 + nf * 16 + l15;
    b1v[nf] = b1[col];
    w2v[nf] = W2[col];
  }
  const float b2s = b2[0];

  // staging constants: thread handles chunk q (8 f32 -> 8 bf16) of rows r0+8*i
  const int q  = tid & 31;     // 0..15 src half, 16..31 dst half
  const int r0 = tid >> 5;     // 0..7
  const int qq = q & 15;
  const bool is_src = (q < 16);
  const int swz = (l15 & 7) << 4;   // row&7 == l15&7 for all our rows

  for (int t = blockIdx.x; t < ntiles; t += gridDim.x) {
    const int t0 = t * BM;

    // ---- stage A tile: gather + f32->bf16 + swizzled ds_write_b128 ----
#pragma unroll 4
    for (int i = 0; i < 16; ++i) {
      const int row = i * 8 + r0;
      const int e = t0 + row;
      if (e < E) {
        const int node = is_src ? eidx[e] : eidx[E + e];
        const float* base = (is_src ? src_emb : dst_emb) + (size_t)node * 128 + qq * 8;
        const float4 f0 = *(const float4*)base;
        const float4 f1 = *(const float4*)(base + 4);
        short8 hv;
        hv[0] = (short)f2bf(f0.x); hv[1] = (short)f2bf(f0.y);
        hv[2] = (short)f2bf(f0.z); hv[3] = (short)f2bf(f0.w);
        hv[4] = (short)f2bf(f1.x); hv[5] = (short)f2bf(f1.y);
        hv[6] = (short)f2bf(f1.z); hv[7] = (short)f2bf(f1.w);
        const int byteoff = row * 512 + ((q * 16) ^ ((row & 7) << 4));
        *(short8*)(Als + byteoff) = hv;
      }
    }
    __syncthreads();

    // ---- MFMA compute + fused epilogue ----
    for (int m = 0; m < 8; ++m) {
      f32x4 acc0 = {0.f, 0.f, 0.f, 0.f};
      f32x4 acc1 = {0.f, 0.f, 0.f, 0.f};
      const int rowb = (m * 16 + l15) * 512;
      const int kb0  = lk8 * 2;
#pragma unroll
      for (int s = 0; s < 8; ++s) {
        const int off = rowb + ((s * 64 + kb0) ^ swz);
        const short8 a = *(const short8*)(Als + off);
        acc0 = __builtin_amdgcn_mfma_f32_16x16x32_bf16(a, bfrag[s][0], acc0, 0, 0, 0);
        acc1 = __builtin_amdgcn_mfma_f32_16x16x32_bf16(a, bfrag[s][1], acc1, 0, 0, 0);
      }
      // h = relu(acc + b1); partial = h . W2 over this wave's 32 cols
      float pr[4];
#pragma unroll
      for (int reg = 0; reg < 4; ++reg) {
        float h0 = acc0[reg] + b1v[0]; h0 = h0 > 0.f ? h0 : 0.f;
        float h1 = acc1[reg] + b1v[1]; h1 = h1 > 0.f ? h1 : 0.f;
        pr[reg] = h0 * w2v[0] + h1 * w2v[1];
      }
#pragma unroll
      for (int off = 1; off < 16; off <<= 1) {
#pragma unroll
        for (int reg = 0; reg < 4; ++reg)
          pr[reg] += __shfl_xor(pr[reg], off, 64);
      }
      if (l15 == 0) {
        const int rbase = m * 16 + (lane >> 4) * 4;
#pragma unroll
        for (int reg = 0; reg < 4; ++reg)
          rowpart[w][rbase + reg] = pr[reg];
      }
    }
    __syncthreads();

    // ---- cross-wave reduce + sigmoid + store ----
    if (tid < BM) {
      const int e = t0 + tid;
      if (e < E) {
        const float sum = rowpart[0][tid] + rowpart[1][tid] +
                          rowpart[2][tid] + rowpart[3][tid] + b2s;
        out[e] = 1.f / (1.f + __expf(-sum));
      }
    }
    __syncthreads();
  }
}

extern "C" void kernel_launch(void* const* d_in, const int* in_sizes, int n_in,
                              void* d_out, int out_size, void* d_ws, size_t ws_size,
                              hipStream_t stream) {
  const float* src = (const float*)d_in[0];
  const float* dst = (const float*)d_in[1];
  const int*   eix = (const int*)d_in[2];
  const float* W1  = (const float*)d_in[3];
  const float* b1  = (const float*)d_in[4];
  const float* W2  = (const float*)d_in[5];
  const float* b2  = (const float*)d_in[6];
  float* out = (float*)d_out;

  const int E = in_sizes[2] / 2;
  const int ntiles = (E + BM - 1) / BM;
  const int grid = ntiles < 1024 ? ntiles : 1024;
  edge_decoder_kernel<<<grid, NTHREADS, 0, stream>>>(src, dst, eix, W1, b1, W2, b2,
                                                     out, E, ntiles);
}

// Round 2
// 109.792 us; speedup vs baseline: 1.4895x; 1.4895x over previous
//
#include <hip/hip_runtime.h>
#include <stdint.h>

#define BM 64
#define NTHREADS 256

typedef __attribute__((ext_vector_type(8))) short short8;
typedef __attribute__((ext_vector_type(4))) float f32x4;

__device__ __forceinline__ unsigned short f2bf(float f) {
  union { float f; uint32_t u; } v; v.f = f;
  uint32_t u = v.u;
  uint32_t r = (u + 0x7FFFu + ((u >> 16) & 1u)) >> 16;
  return (unsigned short)r;
}

// H[E,128] = relu(concat(src,dst)[E,256] @ W1[256,128] + b1); out = sigmoid(H @ W2 + b2)
__global__ __launch_bounds__(NTHREADS, 4)
void edge_decoder_kernel(const float* __restrict__ src_emb,
                         const float* __restrict__ dst_emb,
                         const int* __restrict__ eidx,
                         const float* __restrict__ W1,
                         const float* __restrict__ b1,
                         const float* __restrict__ W2,
                         const float* __restrict__ b2,
                         float* __restrict__ out,
                         int E, int ntiles) {
  // A-tile: BM rows x 256 bf16 (512 B/row), XOR-swizzled within 128B windows
  __shared__ char Als[BM * 512];       // 32 KB
  __shared__ float rowpart[4][BM];     // 1 KB  -> 33 KB total -> 4 blocks/CU

  const int tid  = threadIdx.x;
  const int lane = tid & 63;
  const int w    = tid >> 6;           // wave id 0..3, owns cols [w*32, w*32+32)
  const int l15  = lane & 15;
  const int lk8  = (lane >> 4) * 8;    // k-offset within 32-K block

  // ---- B fragments (W1) -> registers, bf16. ----
  short8 bfrag[8][2];
#pragma unroll
  for (int s = 0; s < 8; ++s) {
#pragma unroll
    for (int nf = 0; nf < 2; ++nf) {
      const int col = w * 32 + nf * 16 + l15;
      short8 t;
#pragma unroll
      for (int j = 0; j < 8; ++j) {
        const int k = s * 32 + lk8 + j;
        t[j] = (short)f2bf(W1[k * 128 + col]);
      }
      bfrag[s][nf] = t;
    }
  }
  float b1v[2], w2v[2];
#pragma unroll
  for (int nf = 0; nf < 2; ++nf) {
    const int col = w * 32 + nf * 16 + l15;
    b1v[nf] = b1[col];
    w2v[nf] = W2[col];
  }
  const float b2s = b2[0];

  // staging constants: thread handles chunk q (8 f32 -> 8 bf16) of rows r0+8*i
  const int q  = tid & 31;     // 0..15 src half, 16..31 dst half
  const int r0 = tid >> 5;     // 0..7
  const int qq = q & 15;
  const bool is_src = (q < 16);
  const int swz = (l15 & 7) << 4;

  for (int t = blockIdx.x; t < ntiles; t += gridDim.x) {
    const int t0 = t * BM;

    // ---- stage A tile: gather + f32->bf16 + swizzled ds_write_b128 ----
#pragma unroll
    for (int i = 0; i < 8; ++i) {
      const int row = i * 8 + r0;
      const int e = t0 + row;
      if (e < E) {
        const int node = is_src ? eidx[e] : eidx[E + e];
        const float* base = (is_src ? src_emb : dst_emb) + (size_t)node * 128 + qq * 8;
        const float4 f0 = *(const float4*)base;
        const float4 f1 = *(const float4*)(base + 4);
        short8 hv;
        hv[0] = (short)f2bf(f0.x); hv[1] = (short)f2bf(f0.y);
        hv[2] = (short)f2bf(f0.z); hv[3] = (short)f2bf(f0.w);
        hv[4] = (short)f2bf(f1.x); hv[5] = (short)f2bf(f1.y);
        hv[6] = (short)f2bf(f1.z); hv[7] = (short)f2bf(f1.w);
        const int byteoff = row * 512 + ((q * 16) ^ ((row & 7) << 4));
        *(short8*)(Als + byteoff) = hv;
      }
    }
    __syncthreads();

    // ---- MFMA compute + fused epilogue ----
    for (int m = 0; m < 4; ++m) {
      f32x4 acc0 = {0.f, 0.f, 0.f, 0.f};
      f32x4 acc1 = {0.f, 0.f, 0.f, 0.f};
      const int rowb = (m * 16 + l15) * 512;
      const int kb0  = lk8 * 2;
#pragma unroll
      for (int s = 0; s < 8; ++s) {
        const int off = rowb + ((s * 64 + kb0) ^ swz);
        const short8 a = *(const short8*)(Als + off);
        acc0 = __builtin_amdgcn_mfma_f32_16x16x32_bf16(a, bfrag[s][0], acc0, 0, 0, 0);
        acc1 = __builtin_amdgcn_mfma_f32_16x16x32_bf16(a, bfrag[s][1], acc1, 0, 0, 0);
      }
      // h = relu(acc + b1); partial = h . W2 over this wave's 32 cols
      float pr[4];
#pragma unroll
      for (int reg = 0; reg < 4; ++reg) {
        float h0 = acc0[reg] + b1v[0]; h0 = h0 > 0.f ? h0 : 0.f;
        float h1 = acc1[reg] + b1v[1]; h1 = h1 > 0.f ? h1 : 0.f;
        pr[reg] = h0 * w2v[0] + h1 * w2v[1];
      }
#pragma unroll
      for (int off = 1; off < 16; off <<= 1) {
#pragma unroll
        for (int reg = 0; reg < 4; ++reg)
          pr[reg] += __shfl_xor(pr[reg], off, 64);
      }
      if (l15 == 0) {
        const int rbase = m * 16 + (lane >> 4) * 4;
#pragma unroll
        for (int reg = 0; reg < 4; ++reg)
          rowpart[w][rbase + reg] = pr[reg];
      }
    }
    __syncthreads();

    // ---- cross-wave reduce + sigmoid + store ----
    if (tid < BM) {
      const int e = t0 + tid;
      if (e < E) {
        const float sum = rowpart[0][tid] + rowpart[1][tid] +
                          rowpart[2][tid] + rowpart[3][tid] + b2s;
        out[e] = 1.f / (1.f + __expf(-sum));
      }
    }
    __syncthreads();
  }
}

extern "C" void kernel_launch(void* const* d_in, const int* in_sizes, int n_in,
                              void* d_out, int out_size, void* d_ws, size_t ws_size,
                              hipStream_t stream) {
  const float* src = (const float*)d_in[0];
  const float* dst = (const float*)d_in[1];
  const int*   eix = (const int*)d_in[2];
  const float* W1  = (const float*)d_in[3];
  const float* b1  = (const float*)d_in[4];
  const float* W2  = (const float*)d_in[5];
  const float* b2  = (const float*)d_in[6];
  float* out = (float*)d_out;

  const int E = in_sizes[2] / 2;
  const int ntiles = (E + BM - 1) / BM;
  const int grid = ntiles < 2048 ? ntiles : 2048;
  edge_decoder_kernel<<<grid, NTHREADS, 0, stream>>>(src, dst, eix, W1, b1, W2, b2,
                                                     out, E, ntiles);
}